// Round 14
// baseline (460.573 us; speedup 1.0000x reference)
//
#include <hip/hip_runtime.h>
#include <hip/hip_bf16.h>
#include <stdint.h>

// Problem dims
#define T_TOK 2048
#define HD    1024
#define NE    8
#define FD    1408
#define F2D   2816
#define HP    1056     // xbf row pitch (bf16)
#define OP    1056     // o row pitch (f32)

// GEMM tiling
#define BM 128
#define BK 32
#define MAXMT 40
#define MAXSLOTS 5120
#define FC1_NT 22      // FD/64
#define FC2_NT 16      // HD/64
#define FC1_NWG (FC1_NT * MAXMT)   // 880
#define FC2_NWG (FC2_NT * MAXMT)   // 640
#define FC1_CHUNK 110
#define FC2_CHUNK 80

typedef __attribute__((ext_vector_type(8))) short bf16x8;
typedef __attribute__((ext_vector_type(4))) float f32x4;
typedef __attribute__((ext_vector_type(2))) int i32x2;

__device__ __forceinline__ unsigned short f2bf(float f) {
  unsigned int u = __float_as_uint(f);
  u += 0x7FFFu + ((u >> 16) & 1u);   // RNE
  return (unsigned short)(u >> 16);
}

#define GLL16(gp, lp) __builtin_amdgcn_global_load_lds( \
    (const __attribute__((address_space(1))) void*)(gp), \
    (__attribute__((address_space(3))) void*)(lp), 16, 0, 0)

#define LDS_OFF(p) ((unsigned)(uintptr_t)(__attribute__((address_space(3))) const unsigned short*)(p))

// Transpose-read pair (verified r10): issue raw, wait at call site, unpack after.
__device__ __forceinline__ void tr_issue(unsigned a, i32x2& lo, i32x2& hi) {
  asm volatile("ds_read_b64_tr_b16 %0, %2\n\t"
               "ds_read_b64_tr_b16 %1, %2 offset:512"
               : "=&v"(lo), "=&v"(hi)
               : "v"(a)
               : "memory");
}
__device__ __forceinline__ bf16x8 tr_pack(i32x2 lo, i32x2 hi) {
  union { i32x2 v; short s[4]; } a, b;
  a.v = lo; b.v = hi;
  bf16x8 f;
  f[0] = a.s[0]; f[1] = a.s[1]; f[2] = a.s[2]; f[3] = a.s[3];
  f[4] = b.s[0]; f[5] = b.s[1]; f[6] = b.s[2]; f[7] = b.s[3];
  return f;
}

// ---------------------------------------------------------------------------
// Router: one wave per token. f32 logits, softmax, top-2, counts; emits x bf16.
// ---------------------------------------------------------------------------
__global__ __launch_bounds__(256) void k_router(
    const float* __restrict__ x, const float* __restrict__ rw,
    unsigned short* __restrict__ xbf, int* __restrict__ ctrl,
    int* __restrict__ tok_e, float* __restrict__ tok_p)
{
  const int lane = threadIdx.x & 63;
  const int t = blockIdx.x * 4 + (threadIdx.x >> 6);
  const float* xr = x + (size_t)t * HD;

  float part[8];
#pragma unroll
  for (int e = 0; e < 8; ++e) part[e] = 0.f;

#pragma unroll
  for (int i = 0; i < 16; ++i) {
    const int h = i * 64 + lane;
    const float xv = xr[h];
    xbf[(size_t)t * HP + h] = f2bf(xv);
    const float4* rwr = reinterpret_cast<const float4*>(rw + (size_t)h * 8);
    float4 a = rwr[0], bb = rwr[1];
    part[0] += xv * a.x; part[1] += xv * a.y; part[2] += xv * a.z; part[3] += xv * a.w;
    part[4] += xv * bb.x; part[5] += xv * bb.y; part[6] += xv * bb.z; part[7] += xv * bb.w;
  }
#pragma unroll
  for (int e = 0; e < 8; ++e) {
    float v = part[e];
#pragma unroll
    for (int d = 32; d; d >>= 1) v += __shfl_xor(v, d, 64);
    part[e] = v;
  }
  float m = part[0];
#pragma unroll
  for (int e = 1; e < 8; ++e) m = fmaxf(m, part[e]);
  float p[8], s = 0.f;
#pragma unroll
  for (int e = 0; e < 8; ++e) { p[e] = __expf(part[e] - m); s += p[e]; }
  const float inv = 1.f / s;
#pragma unroll
  for (int e = 0; e < 8; ++e) p[e] *= inv;

  int e0 = 0; float p0 = p[0];
#pragma unroll
  for (int e = 1; e < 8; ++e) if (p[e] > p0) { p0 = p[e]; e0 = e; }
  int e1 = -1; float p1 = -1.f;
#pragma unroll
  for (int e = 0; e < 8; ++e) if (e != e0 && p[e] > p1) { p1 = p[e]; e1 = e; }

  if (lane == 0) {
    tok_e[t * 2 + 0] = e0; tok_e[t * 2 + 1] = e1;
    tok_p[t * 2 + 0] = p0; tok_p[t * 2 + 1] = p1;
    atomicAdd(&ctrl[e0], 1);
    atomicAdd(&ctrl[e1], 1);
  }
}

// ---------------------------------------------------------------------------
// Offsets + scatter (merged, single block).
// ctrl: [0..7]=cnt [16..23]=off [24..63]=mtE [64..103]=mtB
// ---------------------------------------------------------------------------
__global__ __launch_bounds__(256) void k_offsets(
    int* __restrict__ ctrl, const int* __restrict__ tok_e,
    const float* __restrict__ tok_p, int* __restrict__ stok,
    float* __restrict__ sp, int* __restrict__ tslot,
    int* __restrict__ widmt1, int* __restrict__ widmt2)
{
  __shared__ int soff[8], scnt[8], sFirst[8], sNmt[8], sTake[8], sCur[8];
  __shared__ int sSpill;
  if (threadIdx.x == 0) {
    int o = 0, nm = 0, spill = 0;
    for (int e = 0; e < 8; ++e) {
      ctrl[16 + e] = o; soff[e] = o; scnt[e] = ctrl[e]; sCur[e] = 0;
      const int n = ctrl[e];
      const int nmt = (n + BM - 1) / BM;
      sFirst[e] = nm; sNmt[e] = nmt; sTake[e] = nmt < 5 ? nmt : 5;
      if (nmt > 5) spill = 1;
      for (int j = 0; j < nmt; ++j) { ctrl[24 + nm] = e; ctrl[64 + nm] = o + j * BM; ++nm; }
      o += nmt * BM;
    }
    for (int i = nm; i < MAXMT; ++i) ctrl[24 + i] = -1;
    sSpill = spill;
  }
  __syncthreads();
  for (int i = threadIdx.x; i < FC1_NWG; i += 256) {
    const int e = i / FC1_CHUNK, r = i % FC1_CHUNK;
    const int j = r / FC1_NT, n = r % FC1_NT;
    widmt1[i] = (j < sTake[e]) ? (sFirst[e] + j) * 32 + n : -1;
  }
  for (int i = threadIdx.x; i < FC2_NWG; i += 256) {
    const int e = i / FC2_CHUNK, r = i % FC2_CHUNK;
    const int j = r / FC2_NT, n = r % FC2_NT;
    widmt2[i] = (j < sTake[e]) ? (sFirst[e] + j) * 32 + n : -1;
  }
  __syncthreads();
  if (sSpill && threadIdx.x == 0) {
    int cur = 0;
    for (int e = 0; e < 8; ++e)
      for (int j = 5; j < sNmt[e]; ++j)
        for (int n = 0; n < FC1_NT; ++n) {
          while (widmt1[cur] != -1) ++cur;
          widmt1[cur] = (sFirst[e] + j) * 32 + n;
        }
    cur = 0;
    for (int e = 0; e < 8; ++e)
      for (int j = 5; j < sNmt[e]; ++j)
        for (int n = 0; n < FC2_NT; ++n) {
          while (widmt2[cur] != -1) ++cur;
          widmt2[cur] = (sFirst[e] + j) * 32 + n;
        }
  }
  for (int e = 0; e < 8; ++e) {
    const int n = scnt[e], o = soff[e];
    const int padEnd = (n + BM - 1) / BM * BM;
    for (int j = n + (int)threadIdx.x; j < padEnd; j += 256) {
      stok[o + j] = 0; sp[o + j] = 0.f;
    }
  }
  for (int i = threadIdx.x; i < T_TOK; i += 256) {
#pragma unroll
    for (int k = 0; k < 2; ++k) {
      const int e = tok_e[i * 2 + k];
      const int pos = atomicAdd(&sCur[e], 1);
      const int slot = soff[e] + pos;
      stok[slot] = i; sp[slot] = tok_p[i * 2 + k];
      tslot[i * 2 + k] = slot;
    }
  }
}

// ---------------------------------------------------------------------------
// fc1: y = X[slots] @ w1[e] (gate|up), fused silu(y1)*y2*p -> bf16 g.
// 2-buffer LDS (32 KB total -> 5 blocks/CU), B reg-banks depth-2, per-iter
// issue [BWRITE | ASTAGE(t+1) | BLOAD(t+3)], steady vmcnt(4).
// ---------------------------------------------------------------------------
__global__ __launch_bounds__(256, 5) void k_fc1(
    const unsigned short* __restrict__ xbf,   // [T][HP] bf16
    const float* __restrict__ w1,             // [E][H][2F] f32 (native input)
    const int* __restrict__ ctrl,
    const int* __restrict__ stok,
    const float* __restrict__ sp,
    const int* __restrict__ widmt1,
    unsigned short* __restrict__ g)           // [MAXSLOTS][F] bf16
{
  const int bid = blockIdx.x;
  const int wid = (bid & 7) * FC1_CHUNK + (bid >> 3);
  const int packed = widmt1[wid];
  if (packed < 0) return;
  const int mt = packed >> 5;
  const int e = ctrl[24 + mt];
  const int rowbase = ctrl[64 + mt];
  const int n0 = (packed & 31) * 64;

  __shared__ unsigned short sA[2][BM * BK];   // 8 KB each -> 16 KB
  __shared__ unsigned short sB1[2][64 * BK];  // 4 KB each -> 8 KB
  __shared__ unsigned short sB2[2][64 * BK];  // 8 KB; total 32 KB

  const int tid = threadIdx.x;
  const int lane = tid & 63;
  const int wave = tid >> 6;
  const int wm = wave >> 1, wn = wave & 1;

  const int schunk = (lane & 3) ^ ((lane >> 3) & 3);
  const unsigned short* aSrc[2];
#pragma unroll
  for (int t4 = 0; t4 < 2; ++t4) {
    const int row = (t4 * 4 + wave) * 16 + (lane >> 2);
    const int tok = stok[rowbase + row];
    aSrc[t4] = xbf + (size_t)tok * HP + schunk * 8;
  }

  const int kdec = wave * 8 + ((lane >> 5) << 2) + ((lane >> 1) & 3);
  const int ndec = ((lane >> 3) & 3) * 16 + (lane & 1) * 8;
  const float* b1SrcF = w1 + ((size_t)e * HD + kdec) * F2D + n0 + ndec;
  const float* b2SrcF = b1SrcF + FD;

  const int c = lane >> 4;
  int aoff[4];
#pragma unroll
  for (int m = 0; m < 4; ++m) {
    const int row = wm * 64 + m * 16 + (lane & 15);
    aoff[m] = row * 32 + ((c ^ ((row >> 1) & 3)) << 3);
  }
  const unsigned trlane = (lane & 15) * 8 + (lane >> 4) * 1024;
  unsigned trb[2];
#pragma unroll
  for (int n = 0; n < 2; ++n) trb[n] = trlane + (wn * 2 + n) * 128;
  const unsigned b1base = LDS_OFF(&sB1[0][0]);
  const unsigned b2base = LDS_OFF(&sB2[0][0]);

  const f32x4 zero = {0.f, 0.f, 0.f, 0.f};
  f32x4 acc1[4][2], acc2[4][2];
#pragma unroll
  for (int m = 0; m < 4; ++m)
#pragma unroll
    for (int n = 0; n < 2; ++n) { acc1[m][n] = zero; acc2[m][n] = zero; }

  // two named register banks per stream (static indexing)
  float b1r0[8], b2r0[8], b1r1[8], b2r1[8];

#define FC1_BLOAD(KT, R1, R2) do {                                  \
    const float* _p1 = b1SrcF + (size_t)(KT) * BK * F2D;            \
    const float* _p2 = b2SrcF + (size_t)(KT) * BK * F2D;            \
    *(float4*)&R1[0] = *(const float4*)_p1;                         \
    *(float4*)&R1[4] = *(const float4*)(_p1 + 4);                   \
    *(float4*)&R2[0] = *(const float4*)_p2;                         \
    *(float4*)&R2[4] = *(const float4*)(_p2 + 4);                   \
  } while (0)

#define FC1_BWRITE(BUF, R1, R2) do {                                \
    unsigned _a0,_a1,_a2,_a3,_c0,_c1,_c2,_c3;                       \
    asm("v_cvt_pk_bf16_f32 %0, %1, %2" : "=v"(_a0) : "v"(R1[0]), "v"(R1[1])); \
    asm("v_cvt_pk_bf16_f32 %0, %1, %2" : "=v"(_a1) : "v"(R1[2]), "v"(R1[3])); \
    asm("v_cvt_pk_bf16_f32 %0, %1, %2" : "=v"(_a2) : "v"(R1[4]), "v"(R1[5])); \
    asm("v_cvt_pk_bf16_f32 %0, %1, %2" : "=v"(_a3) : "v"(R1[6]), "v"(R1[7])); \
    asm("v_cvt_pk_bf16_f32 %0, %1, %2" : "=v"(_c0) : "v"(R2[0]), "v"(R2[1])); \
    asm("v_cvt_pk_bf16_f32 %0, %1, %2" : "=v"(_c1) : "v"(R2[2]), "v"(R2[3])); \
    asm("v_cvt_pk_bf16_f32 %0, %1, %2" : "=v"(_c2) : "v"(R2[4]), "v"(R2[5])); \
    asm("v_cvt_pk_bf16_f32 %0, %1, %2" : "=v"(_c3) : "v"(R2[6]), "v"(R2[7])); \
    uint4 _u1 = make_uint4(_a0,_a1,_a2,_a3);                        \
    uint4 _u2 = make_uint4(_c0,_c1,_c2,_c3);                        \
    *(uint4*)&sB1[BUF][wave * 512 + lane * 8] = _u1;                \
    *(uint4*)&sB2[BUF][wave * 512 + lane * 8] = _u2;                \
  } while (0)

#define FC1_ASTAGE(BUF, KT) do {                                    \
    for (int _t4 = 0; _t4 < 2; ++_t4)                               \
      GLL16(aSrc[_t4] + (size_t)(KT) * BK, &sA[BUF][(_t4 * 4 + wave) * 512]); \
  } while (0)

  const int NSTEP = HD / BK;   // 32
  // ---- prologue: lands queue [B1:4, A0:2, B2:4] ----
  FC1_BLOAD(0, b1r0, b2r0);
  __builtin_amdgcn_sched_barrier(0);
  asm volatile("s_waitcnt vmcnt(0)" ::: "memory");
  FC1_BWRITE(0, b1r0, b2r0);
  __builtin_amdgcn_sched_barrier(0);
  FC1_BLOAD(1, b1r1, b2r1);
  __builtin_amdgcn_sched_barrier(0);
  FC1_ASTAGE(0, 0);
  __builtin_amdgcn_sched_barrier(0);
  FC1_BLOAD(2, b1r0, b2r0);
  __builtin_amdgcn_sched_barrier(0);
  asm volatile("s_waitcnt lgkmcnt(0)" ::: "memory");   // BWRITE(0) drained

// per-iter: wait vmcnt(4) drains B(t+1)+A(t), leaves B(t+2).
// CB = t&1 compute bank, NB = CB^1.
#define FC1_STEP(T, R1, R2) do {                                             \
    const int _t = (T);                                                      \
    if (_t < NSTEP - 2) { asm volatile("s_waitcnt vmcnt(4)" ::: "memory"); } \
    else                { asm volatile("s_waitcnt vmcnt(0)" ::: "memory"); } \
    __builtin_amdgcn_s_barrier();                                            \
    __builtin_amdgcn_sched_barrier(0);                                       \
    const int _cb = _t & 1;                                                  \
    const int _nb = _cb ^ 1;                                                 \
    if (_t + 1 < NSTEP) FC1_BWRITE(_nb, R1, R2);                             \
    __builtin_amdgcn_sched_barrier(0);                                       \
    if (_t + 1 < NSTEP) FC1_ASTAGE(_nb, _t + 1);                             \
    __builtin_amdgcn_sched_barrier(0);                                       \
    if (_t + 3 < NSTEP) FC1_BLOAD(_t + 3, R1, R2);                           \
    __builtin_amdgcn_sched_barrier(0);                                       \
    bf16x8 _af[4];                                                           \
    for (int _m = 0; _m < 4; ++_m)                                           \
      _af[_m] = *(const bf16x8*)&sA[_cb][aoff[_m]];                          \
    __builtin_amdgcn_sched_barrier(0);                                       \
    i32x2 _q1lo[2], _q1hi[2], _q2lo[2], _q2hi[2];                            \
    tr_issue(b1base + _cb * 4096 + trb[0], _q1lo[0], _q1hi[0]);              \
    tr_issue(b2base + _cb * 4096 + trb[0], _q2lo[0], _q2hi[0]);              \
    __builtin_amdgcn_sched_barrier(0);                                       \
    tr_issue(b1base + _cb * 4096 + trb[1], _q1lo[1], _q1hi[1]);              \
    tr_issue(b2base + _cb * 4096 + trb[1], _q2lo[1], _q2hi[1]);              \
    asm volatile("s_waitcnt lgkmcnt(4)" ::: "memory");                       \
    __builtin_amdgcn_sched_barrier(0);                                       \
    bf16x8 _b1f0 = tr_pack(_q1lo[0], _q1hi[0]);                              \
    bf16x8 _b2f0 = tr_pack(_q2lo[0], _q2hi[0]);                              \
    __builtin_amdgcn_s_setprio(1);                                           \
    for (int _m = 0; _m < 4; ++_m) {                                         \
      acc1[_m][0] = __builtin_amdgcn_mfma_f32_16x16x32_bf16(_af[_m], _b1f0, acc1[_m][0], 0, 0, 0); \
      acc2[_m][0] = __builtin_amdgcn_mfma_f32_16x16x32_bf16(_af[_m], _b2f0, acc2[_m][0], 0, 0, 0); \
    }                                                                        \
    __builtin_amdgcn_s_setprio(0);                                           \
    asm volatile("s_waitcnt lgkmcnt(0)" ::: "memory");                       \
    __builtin_amdgcn_sched_barrier(0);                                       \
    bf16x8 _b1f1 = tr_pack(_q1lo[1], _q1hi[1]);                              \
    bf16x8 _b2f1 = tr_pack(_q2lo[1], _q2hi[1]);                              \
    __builtin_amdgcn_s_setprio(1);                                           \
    for (int _m = 0; _m < 4; ++_m) {                                         \
      acc1[_m][1] = __builtin_amdgcn_mfma_f32_16x16x32_bf16(_af[_m], _b1f1, acc1[_m][1], 0, 0, 0); \
      acc2[_m][1] = __builtin_amdgcn_mfma_f32_16x16x32_bf16(_af[_m], _b2f1, acc2[_m][1], 0, 0, 0); \
    }                                                                        \
    __builtin_amdgcn_s_setprio(0);                                           \
  } while (0)

  for (int tt = 0; tt < NSTEP; tt += 2) {
    FC1_STEP(tt, b1r1, b2r1);       // even t: bank1 regs
    FC1_STEP(tt + 1, b1r0, b2r0);   // odd t: bank0 regs
  }

  float prv[4][4];
#pragma unroll
  for (int m = 0; m < 4; ++m)
#pragma unroll
    for (int r = 0; r < 4; ++r)
      prv[m][r] = sp[rowbase + wm * 64 + m * 16 + (lane >> 4) * 4 + r];

#pragma unroll
  for (int m = 0; m < 4; ++m) {
    const int rb = rowbase + wm * 64 + m * 16 + (lane >> 4) * 4;
#pragma unroll
    for (int n = 0; n < 2; ++n) {
      const int col = n0 + wn * 32 + n * 16 + (lane & 15);
#pragma unroll
      for (int r = 0; r < 4; ++r) {
        const float y1 = acc1[m][n][r];
        const float y2 = acc2[m][n][r];
        const float gv = y1 / (1.f + __expf(-y1)) * y2 * prv[m][r];
        g[(size_t)(rb + r) * FD + col] = f2bf(gv);
      }
    }
  }
}

// ---------------------------------------------------------------------------
// fc2: o[slot] = g[slot] @ w2[e] -- 2-buffer LDS (24 KB), depth-2 B banks,
// per-iter [BWRITE | ASTAGE(t+1) | BLOAD(t+3)], steady vmcnt(2).
// ---------------------------------------------------------------------------
__global__ __launch_bounds__(256, 5) void k_fc2(
    const unsigned short* __restrict__ g,     // [MAXSLOTS][F] bf16
    const float* __restrict__ w2,             // [E][F][H] f32 (native input)
    const int* __restrict__ ctrl,
    const int* __restrict__ widmt2,
    float* __restrict__ o)                    // [MAXSLOTS][OP] f32
{
  const int bid = blockIdx.x;
  const int wid = (bid & 7) * FC2_CHUNK + (bid >> 3);
  const int packed = widmt2[wid];
  if (packed < 0) return;
  const int mt = packed >> 5;
  const int e = ctrl[24 + mt];
  const int rowbase = ctrl[64 + mt];
  const int n0 = (packed & 31) * 64;

  __shared__ unsigned short sA[2][BM * BK];   // 16 KB
  __shared__ unsigned short sB[2][64 * BK];   // 8 KB; total 24 KB

  const int tid = threadIdx.x;
  const int lane = tid & 63;
  const int wave = tid >> 6;
  const int wm = wave >> 1, wn = wave & 1;

  const int schunk = (lane & 3) ^ ((lane >> 3) & 3);
  const unsigned short* aSrc[2];
#pragma unroll
  for (int t4 = 0; t4 < 2; ++t4) {
    const int row = (t4 * 4 + wave) * 16 + (lane >> 2);
    aSrc[t4] = g + (size_t)(rowbase + row) * FD + schunk * 8;
  }

  const int kdec = wave * 8 + ((lane >> 5) << 2) + ((lane >> 1) & 3);
  const int ndec = ((lane >> 3) & 3) * 16 + (lane & 1) * 8;
  const float* bSrcF = w2 + ((size_t)e * FD + kdec) * HD + n0 + ndec;

  const int c = lane >> 4;
  int aoff[4];
#pragma unroll
  for (int m = 0; m < 4; ++m) {
    const int row = wm * 64 + m * 16 + (lane & 15);
    aoff[m] = row * 32 + ((c ^ ((row >> 1) & 3)) << 3);
  }
  const unsigned trlane = (lane & 15) * 8 + (lane >> 4) * 1024;
  unsigned trb[2];
#pragma unroll
  for (int n = 0; n < 2; ++n) trb[n] = trlane + (wn * 2 + n) * 128;
  const unsigned bbase = LDS_OFF(&sB[0][0]);

  const f32x4 zero = {0.f, 0.f, 0.f, 0.f};
  f32x4 acc[4][2];
#pragma unroll
  for (int m = 0; m < 4; ++m)
#pragma unroll
    for (int n = 0; n < 2; ++n) acc[m][n] = zero;

  float br0[8], br1[8];

#define FC2_BLOAD(KT, R) do {                                       \
    const float* _p = bSrcF + (size_t)(KT) * BK * HD;               \
    *(float4*)&R[0] = *(const float4*)_p;                           \
    *(float4*)&R[4] = *(const float4*)(_p + 4);                     \
  } while (0)

#define FC2_BWRITE(BUF, R) do {                                     \
    unsigned _a0,_a1,_a2,_a3;                                       \
    asm("v_cvt_pk_bf16_f32 %0, %1, %2" : "=v"(_a0) : "v"(R[0]), "v"(R[1])); \
    asm("v_cvt_pk_bf16_f32 %0, %1, %2" : "=v"(_a1) : "v"(R[2]), "v"(R[3])); \
    asm("v_cvt_pk_bf16_f32 %0, %1, %2" : "=v"(_a2) : "v"(R[4]), "v"(R[5])); \
    asm("v_cvt_pk_bf16_f32 %0, %1, %2" : "=v"(_a3) : "v"(R[6]), "v"(R[7])); \
    uint4 _u = make_uint4(_a0,_a1,_a2,_a3);                         \
    *(uint4*)&sB[BUF][wave * 512 + lane * 8] = _u;                  \
  } while (0)

#define FC2_ASTAGE(BUF, KT) do {                                    \
    for (int _t4 = 0; _t4 < 2; ++_t4)                               \
      GLL16(aSrc[_t4] + (size_t)(KT) * BK, &sA[BUF][(_t4 * 4 + wave) * 512]); \
  } while (0)

  const int NSTEP = FD / BK;   // 44
  // ---- prologue: lands queue [B1:2, A0:2, B2:2] ----
  FC2_BLOAD(0, br0);
  __builtin_amdgcn_sched_barrier(0);
  asm volatile("s_waitcnt vmcnt(0)" ::: "memory");
  FC2_BWRITE(0, br0);
  __builtin_amdgcn_sched_barrier(0);
  FC2_BLOAD(1, br1);
  __builtin_amdgcn_sched_barrier(0);
  FC2_ASTAGE(0, 0);
  __builtin_amdgcn_sched_barrier(0);
  FC2_BLOAD(2, br0);
  __builtin_amdgcn_sched_barrier(0);
  asm volatile("s_waitcnt lgkmcnt(0)" ::: "memory");

#define FC2_STEP(T, R) do {                                                  \
    const int _t = (T);                                                      \
    if (_t < NSTEP - 2) { asm volatile("s_waitcnt vmcnt(2)" ::: "memory"); } \
    else                { asm volatile("s_waitcnt vmcnt(0)" ::: "memory"); } \
    __builtin_amdgcn_s_barrier();                                            \
    __builtin_amdgcn_sched_barrier(0);                                       \
    const int _cb = _t & 1;                                                  \
    const int _nb = _cb ^ 1;                                                 \
    if (_t + 1 < NSTEP) FC2_BWRITE(_nb, R);                                  \
    __builtin_amdgcn_sched_barrier(0);                                       \
    if (_t + 1 < NSTEP) FC2_ASTAGE(_nb, _t + 1);                             \
    __builtin_amdgcn_sched_barrier(0);                                       \
    if (_t + 3 < NSTEP) FC2_BLOAD(_t + 3, R);                                \
    __builtin_amdgcn_sched_barrier(0);                                       \
    bf16x8 _af[4];                                                           \
    for (int _m = 0; _m < 4; ++_m)                                           \
      _af[_m] = *(const bf16x8*)&sA[_cb][aoff[_m]];                          \
    __builtin_amdgcn_sched_barrier(0);                                       \
    i32x2 _qlo[2], _qhi[2];                                                  \
    tr_issue(bbase + _cb * 4096 + trb[0], _qlo[0], _qhi[0]);                 \
    __builtin_amdgcn_sched_barrier(0);                                       \
    tr_issue(bbase + _cb * 4096 + trb[1], _qlo[1], _qhi[1]);                 \
    asm volatile("s_waitcnt lgkmcnt(2)" ::: "memory");                       \
    __builtin_amdgcn_sched_barrier(0);                                       \
    bf16x8 _bf0 = tr_pack(_qlo[0], _qhi[0]);                                 \
    __builtin_amdgcn_s_setprio(1);                                           \
    for (int _m = 0; _m < 4; ++_m)                                           \
      acc[_m][0] = __builtin_amdgcn_mfma_f32_16x16x32_bf16(_af[_m], _bf0, acc[_m][0], 0, 0, 0); \
    __builtin_amdgcn_s_setprio(0);                                           \
    asm volatile("s_waitcnt lgkmcnt(0)" ::: "memory");                       \
    __builtin_amdgcn_sched_barrier(0);                                       \
    bf16x8 _bf1 = tr_pack(_qlo[1], _qhi[1]);                                 \
    __builtin_amdgcn_s_setprio(1);                                           \
    for (int _m = 0; _m < 4; ++_m)                                           \
      acc[_m][1] = __builtin_amdgcn_mfma_f32_16x16x32_bf16(_af[_m], _bf1, acc[_m][1], 0, 0, 0); \
    __builtin_amdgcn_s_setprio(0);                                           \
  } while (0)

  for (int tt = 0; tt < NSTEP; tt += 2) {
    FC2_STEP(tt, br1);       // even t: bank1 regs
    FC2_STEP(tt + 1, br0);   // odd t: bank0 regs
  }

#pragma unroll
  for (int m = 0; m < 4; ++m) {
    const int rb = rowbase + wm * 64 + m * 16 + (lane >> 4) * 4;
#pragma unroll
    for (int n = 0; n < 2; ++n) {
      const int col = n0 + wn * 32 + n * 16 + (lane & 15);
#pragma unroll
      for (int r = 0; r < 4; ++r)
        o[(size_t)(rb + r) * OP + col] = acc[m][n][r];
    }
  }
}

// ---------------------------------------------------------------------------
// Combine (unchanged).
// ---------------------------------------------------------------------------
__global__ __launch_bounds__(256) void k_combine(
    const float* __restrict__ o, const int* __restrict__ tslot,
    float* __restrict__ out)
{
  const int t = blockIdx.x;
  const int c4 = threadIdx.x;
  const int sA = tslot[t * 2], sB = tslot[t * 2 + 1];
  const float4 a = reinterpret_cast<const float4*>(o + (size_t)sA * OP)[c4];
  const float4 b = reinterpret_cast<const float4*>(o + (size_t)sB * OP)[c4];
  float4 r;
  r.x = a.x + b.x; r.y = a.y + b.y; r.z = a.z + b.z; r.w = a.w + b.w;
  reinterpret_cast<float4*>(out)[(size_t)t * 256 + c4] = r;
}

// ---------------------------------------------------------------------------
extern "C" void kernel_launch(void* const* d_in, const int* in_sizes, int n_in,
                              void* d_out, int out_size, void* d_ws, size_t ws_size,
                              hipStream_t stream)
{
  const float* x  = (const float*)d_in[0];   // [2048,1,1024]
  const float* rw = (const float*)d_in[1];   // [1024,8]
  const float* w1 = (const float*)d_in[2];   // [8,1024,2816]
  const float* w2 = (const float*)d_in[3];   // [8,1408,1024]
  float* out = (float*)d_out;
  char* ws = (char*)d_ws;

  // ws layout (bytes)
  int*   ctrl   = (int*)(ws + 0);
  int*   tok_e  = (int*)(ws + 1024);
  float* tok_p  = (float*)(ws + 17408);
  int*   stok   = (int*)(ws + 33792);
  float* sp     = (float*)(ws + 54272);
  int*   tslot  = (int*)(ws + 74752);
  int*   widmt1 = (int*)(ws + 91136);
  int*   widmt2 = (int*)(ws + 94656);
  unsigned short* xbf = (unsigned short*)(ws + 97280);   // [T][HP]     4.33 MB
  unsigned short* g   = (unsigned short*)(ws + 4422656); // [SLOTS][F]  14.5 MB
  float*          o   = (float*)(ws + 18840576);         // [SLOTS][OP] 21.6 MB

  hipMemsetAsync(ws, 0, 1024, stream);

  k_router<<<T_TOK / 4, 256, 0, stream>>>(x, rw, xbf, ctrl, tok_e, tok_p);
  k_offsets<<<1, 256, 0, stream>>>(ctrl, tok_e, tok_p, stok, sp, tslot, widmt1, widmt2);
  k_fc1<<<FC1_NWG, 256, 0, stream>>>(xbf, w1, ctrl, stok, sp, widmt1, g);
  k_fc2<<<FC2_NWG, 256, 0, stream>>>(g, w2, ctrl, widmt2, o);
  k_combine<<<T_TOK, 256, 0, stream>>>(o, tslot, out);
}

// Round 15
// 170.355 us; speedup vs baseline: 2.7036x; 2.7036x over previous
//
#include <hip/hip_runtime.h>
#include <hip/hip_bf16.h>
#include <stdint.h>

// Problem dims
#define T_TOK 2048
#define HD    1024
#define NE    8
#define FD    1408
#define F2D   2816
#define HP    1056     // xbf row pitch (bf16)
#define OP    1056     // o row pitch (f32)

// GEMM tiling
#define BM 128
#define BK 32
#define MAXMT 40
#define MAXSLOTS 5120
#define FC1_NT 22      // FD/64
#define FC2_NT 16      // HD/64
#define FC1_NWG (FC1_NT * MAXMT)   // 880
#define FC2_NWG (FC2_NT * MAXMT)   // 640
#define FC1_CHUNK 110
#define FC2_CHUNK 80

typedef __attribute__((ext_vector_type(8))) short bf16x8;
typedef __attribute__((ext_vector_type(4))) float f32x4;
typedef __attribute__((ext_vector_type(2))) int i32x2;

__device__ __forceinline__ unsigned short f2bf(float f) {
  unsigned int u = __float_as_uint(f);
  u += 0x7FFFu + ((u >> 16) & 1u);   // RNE
  return (unsigned short)(u >> 16);
}

#define GLL16(gp, lp) __builtin_amdgcn_global_load_lds( \
    (const __attribute__((address_space(1))) void*)(gp), \
    (__attribute__((address_space(3))) void*)(lp), 16, 0, 0)

#define LDS_OFF(p) ((unsigned)(uintptr_t)(__attribute__((address_space(3))) const unsigned short*)(p))

// Transpose-read pair (verified r10): issue raw, wait at call site, unpack after.
__device__ __forceinline__ void tr_issue(unsigned a, i32x2& lo, i32x2& hi) {
  asm volatile("ds_read_b64_tr_b16 %0, %2\n\t"
               "ds_read_b64_tr_b16 %1, %2 offset:512"
               : "=&v"(lo), "=&v"(hi)
               : "v"(a)
               : "memory");
}
__device__ __forceinline__ bf16x8 tr_pack(i32x2 lo, i32x2 hi) {
  union { i32x2 v; short s[4]; } a, b;
  a.v = lo; b.v = hi;
  bf16x8 f;
  f[0] = a.s[0]; f[1] = a.s[1]; f[2] = a.s[2]; f[3] = a.s[3];
  f[4] = b.s[0]; f[5] = b.s[1]; f[6] = b.s[2]; f[7] = b.s[3];
  return f;
}

// ---------------------------------------------------------------------------
// Router: one wave per token. f32 logits, softmax, top-2, counts; emits x bf16.
// ---------------------------------------------------------------------------
__global__ __launch_bounds__(256) void k_router(
    const float* __restrict__ x, const float* __restrict__ rw,
    unsigned short* __restrict__ xbf, int* __restrict__ ctrl,
    int* __restrict__ tok_e, float* __restrict__ tok_p)
{
  const int lane = threadIdx.x & 63;
  const int t = blockIdx.x * 4 + (threadIdx.x >> 6);
  const float* xr = x + (size_t)t * HD;

  float part[8];
#pragma unroll
  for (int e = 0; e < 8; ++e) part[e] = 0.f;

#pragma unroll
  for (int i = 0; i < 16; ++i) {
    const int h = i * 64 + lane;
    const float xv = xr[h];
    xbf[(size_t)t * HP + h] = f2bf(xv);
    const float4* rwr = reinterpret_cast<const float4*>(rw + (size_t)h * 8);
    float4 a = rwr[0], bb = rwr[1];
    part[0] += xv * a.x; part[1] += xv * a.y; part[2] += xv * a.z; part[3] += xv * a.w;
    part[4] += xv * bb.x; part[5] += xv * bb.y; part[6] += xv * bb.z; part[7] += xv * bb.w;
  }
#pragma unroll
  for (int e = 0; e < 8; ++e) {
    float v = part[e];
#pragma unroll
    for (int d = 32; d; d >>= 1) v += __shfl_xor(v, d, 64);
    part[e] = v;
  }
  float m = part[0];
#pragma unroll
  for (int e = 1; e < 8; ++e) m = fmaxf(m, part[e]);
  float p[8], s = 0.f;
#pragma unroll
  for (int e = 0; e < 8; ++e) { p[e] = __expf(part[e] - m); s += p[e]; }
  const float inv = 1.f / s;
#pragma unroll
  for (int e = 0; e < 8; ++e) p[e] *= inv;

  int e0 = 0; float p0 = p[0];
#pragma unroll
  for (int e = 1; e < 8; ++e) if (p[e] > p0) { p0 = p[e]; e0 = e; }
  int e1 = -1; float p1 = -1.f;
#pragma unroll
  for (int e = 0; e < 8; ++e) if (e != e0 && p[e] > p1) { p1 = p[e]; e1 = e; }

  if (lane == 0) {
    tok_e[t * 2 + 0] = e0; tok_e[t * 2 + 1] = e1;
    tok_p[t * 2 + 0] = p0; tok_p[t * 2 + 1] = p1;
    atomicAdd(&ctrl[e0], 1);
    atomicAdd(&ctrl[e1], 1);
  }
}

// ---------------------------------------------------------------------------
// Offsets + scatter (merged, single block).
// ctrl: [0..7]=cnt [16..23]=off [24..63]=mtE [64..103]=mtB
// ---------------------------------------------------------------------------
__global__ __launch_bounds__(256) void k_offsets(
    int* __restrict__ ctrl, const int* __restrict__ tok_e,
    const float* __restrict__ tok_p, int* __restrict__ stok,
    float* __restrict__ sp, int* __restrict__ tslot,
    int* __restrict__ widmt1, int* __restrict__ widmt2)
{
  __shared__ int soff[8], scnt[8], sFirst[8], sNmt[8], sTake[8], sCur[8];
  __shared__ int sSpill;
  if (threadIdx.x == 0) {
    int o = 0, nm = 0, spill = 0;
    for (int e = 0; e < 8; ++e) {
      ctrl[16 + e] = o; soff[e] = o; scnt[e] = ctrl[e]; sCur[e] = 0;
      const int n = ctrl[e];
      const int nmt = (n + BM - 1) / BM;
      sFirst[e] = nm; sNmt[e] = nmt; sTake[e] = nmt < 5 ? nmt : 5;
      if (nmt > 5) spill = 1;
      for (int j = 0; j < nmt; ++j) { ctrl[24 + nm] = e; ctrl[64 + nm] = o + j * BM; ++nm; }
      o += nmt * BM;
    }
    for (int i = nm; i < MAXMT; ++i) ctrl[24 + i] = -1;
    sSpill = spill;
  }
  __syncthreads();
  for (int i = threadIdx.x; i < FC1_NWG; i += 256) {
    const int e = i / FC1_CHUNK, r = i % FC1_CHUNK;
    const int j = r / FC1_NT, n = r % FC1_NT;
    widmt1[i] = (j < sTake[e]) ? (sFirst[e] + j) * 32 + n : -1;
  }
  for (int i = threadIdx.x; i < FC2_NWG; i += 256) {
    const int e = i / FC2_CHUNK, r = i % FC2_CHUNK;
    const int j = r / FC2_NT, n = r % FC2_NT;
    widmt2[i] = (j < sTake[e]) ? (sFirst[e] + j) * 32 + n : -1;
  }
  __syncthreads();
  if (sSpill && threadIdx.x == 0) {
    int cur = 0;
    for (int e = 0; e < 8; ++e)
      for (int j = 5; j < sNmt[e]; ++j)
        for (int n = 0; n < FC1_NT; ++n) {
          while (widmt1[cur] != -1) ++cur;
          widmt1[cur] = (sFirst[e] + j) * 32 + n;
        }
    cur = 0;
    for (int e = 0; e < 8; ++e)
      for (int j = 5; j < sNmt[e]; ++j)
        for (int n = 0; n < FC2_NT; ++n) {
          while (widmt2[cur] != -1) ++cur;
          widmt2[cur] = (sFirst[e] + j) * 32 + n;
        }
  }
  for (int e = 0; e < 8; ++e) {
    const int n = scnt[e], o = soff[e];
    const int padEnd = (n + BM - 1) / BM * BM;
    for (int j = n + (int)threadIdx.x; j < padEnd; j += 256) {
      stok[o + j] = 0; sp[o + j] = 0.f;
    }
  }
  for (int i = threadIdx.x; i < T_TOK; i += 256) {
#pragma unroll
    for (int k = 0; k < 2; ++k) {
      const int e = tok_e[i * 2 + k];
      const int pos = atomicAdd(&sCur[e], 1);
      const int slot = soff[e] + pos;
      stok[slot] = i; sp[slot] = tok_p[i * 2 + k];
      tslot[i * 2 + k] = slot;
    }
  }
}

// ---------------------------------------------------------------------------
// fc1: y = X[slots] @ w1[e] (gate|up), fused silu(y1)*y2*p -> bf16 g.
// 2-buffer LDS (32 KB -> 5 blocks/CU by LDS; VGPR ~92 -> 4 blocks/CU),
// B reg-banks depth-2, per-iter [BWRITE | ASTAGE(t+1) | BLOAD(t+3)],
// steady vmcnt(4). NO min-waves clause (r14's ,5 forced spills).
// ---------------------------------------------------------------------------
__global__ __launch_bounds__(256) void k_fc1(
    const unsigned short* __restrict__ xbf,   // [T][HP] bf16
    const float* __restrict__ w1,             // [E][H][2F] f32 (native input)
    const int* __restrict__ ctrl,
    const int* __restrict__ stok,
    const float* __restrict__ sp,
    const int* __restrict__ widmt1,
    unsigned short* __restrict__ g)           // [MAXSLOTS][F] bf16
{
  const int bid = blockIdx.x;
  const int wid = (bid & 7) * FC1_CHUNK + (bid >> 3);
  const int packed = widmt1[wid];
  if (packed < 0) return;
  const int mt = packed >> 5;
  const int e = ctrl[24 + mt];
  const int rowbase = ctrl[64 + mt];
  const int n0 = (packed & 31) * 64;

  __shared__ unsigned short sA[2][BM * BK];   // 8 KB each -> 16 KB
  __shared__ unsigned short sB1[2][64 * BK];  // 4 KB each -> 8 KB
  __shared__ unsigned short sB2[2][64 * BK];  // 8 KB; total 32 KB

  const int tid = threadIdx.x;
  const int lane = tid & 63;
  const int wave = tid >> 6;
  const int wm = wave >> 1, wn = wave & 1;

  const int schunk = (lane & 3) ^ ((lane >> 3) & 3);
  const unsigned short* aSrc[2];
#pragma unroll
  for (int t4 = 0; t4 < 2; ++t4) {
    const int row = (t4 * 4 + wave) * 16 + (lane >> 2);
    const int tok = stok[rowbase + row];
    aSrc[t4] = xbf + (size_t)tok * HP + schunk * 8;
  }

  const int kdec = wave * 8 + ((lane >> 5) << 2) + ((lane >> 1) & 3);
  const int ndec = ((lane >> 3) & 3) * 16 + (lane & 1) * 8;
  const float* b1SrcF = w1 + ((size_t)e * HD + kdec) * F2D + n0 + ndec;
  const float* b2SrcF = b1SrcF + FD;

  const int c = lane >> 4;
  int aoff[4];
#pragma unroll
  for (int m = 0; m < 4; ++m) {
    const int row = wm * 64 + m * 16 + (lane & 15);
    aoff[m] = row * 32 + ((c ^ ((row >> 1) & 3)) << 3);
  }
  const unsigned trlane = (lane & 15) * 8 + (lane >> 4) * 1024;
  unsigned trb[2];
#pragma unroll
  for (int n = 0; n < 2; ++n) trb[n] = trlane + (wn * 2 + n) * 128;
  const unsigned b1base = LDS_OFF(&sB1[0][0]);
  const unsigned b2base = LDS_OFF(&sB2[0][0]);

  const f32x4 zero = {0.f, 0.f, 0.f, 0.f};
  f32x4 acc1[4][2], acc2[4][2];
#pragma unroll
  for (int m = 0; m < 4; ++m)
#pragma unroll
    for (int n = 0; n < 2; ++n) { acc1[m][n] = zero; acc2[m][n] = zero; }

  // two named register banks per stream (static indexing)
  float b1r0[8], b2r0[8], b1r1[8], b2r1[8];

#define FC1_BLOAD(KT, R1, R2) do {                                  \
    const float* _p1 = b1SrcF + (size_t)(KT) * BK * F2D;            \
    const float* _p2 = b2SrcF + (size_t)(KT) * BK * F2D;            \
    *(float4*)&R1[0] = *(const float4*)_p1;                         \
    *(float4*)&R1[4] = *(const float4*)(_p1 + 4);                   \
    *(float4*)&R2[0] = *(const float4*)_p2;                         \
    *(float4*)&R2[4] = *(const float4*)(_p2 + 4);                   \
  } while (0)

#define FC1_BWRITE(BUF, R1, R2) do {                                \
    unsigned _a0,_a1,_a2,_a3,_c0,_c1,_c2,_c3;                       \
    asm("v_cvt_pk_bf16_f32 %0, %1, %2" : "=v"(_a0) : "v"(R1[0]), "v"(R1[1])); \
    asm("v_cvt_pk_bf16_f32 %0, %1, %2" : "=v"(_a1) : "v"(R1[2]), "v"(R1[3])); \
    asm("v_cvt_pk_bf16_f32 %0, %1, %2" : "=v"(_a2) : "v"(R1[4]), "v"(R1[5])); \
    asm("v_cvt_pk_bf16_f32 %0, %1, %2" : "=v"(_a3) : "v"(R1[6]), "v"(R1[7])); \
    asm("v_cvt_pk_bf16_f32 %0, %1, %2" : "=v"(_c0) : "v"(R2[0]), "v"(R2[1])); \
    asm("v_cvt_pk_bf16_f32 %0, %1, %2" : "=v"(_c1) : "v"(R2[2]), "v"(R2[3])); \
    asm("v_cvt_pk_bf16_f32 %0, %1, %2" : "=v"(_c2) : "v"(R2[4]), "v"(R2[5])); \
    asm("v_cvt_pk_bf16_f32 %0, %1, %2" : "=v"(_c3) : "v"(R2[6]), "v"(R2[7])); \
    uint4 _u1 = make_uint4(_a0,_a1,_a2,_a3);                        \
    uint4 _u2 = make_uint4(_c0,_c1,_c2,_c3);                        \
    *(uint4*)&sB1[BUF][wave * 512 + lane * 8] = _u1;                \
    *(uint4*)&sB2[BUF][wave * 512 + lane * 8] = _u2;                \
  } while (0)

#define FC1_ASTAGE(BUF, KT) do {                                    \
    for (int _t4 = 0; _t4 < 2; ++_t4)                               \
      GLL16(aSrc[_t4] + (size_t)(KT) * BK, &sA[BUF][(_t4 * 4 + wave) * 512]); \
  } while (0)

  const int NSTEP = HD / BK;   // 32
  // ---- prologue: lands queue [B1:4, A0:2, B2:4] ----
  FC1_BLOAD(0, b1r0, b2r0);
  __builtin_amdgcn_sched_barrier(0);
  asm volatile("s_waitcnt vmcnt(0)" ::: "memory");
  FC1_BWRITE(0, b1r0, b2r0);
  __builtin_amdgcn_sched_barrier(0);
  FC1_BLOAD(1, b1r1, b2r1);
  __builtin_amdgcn_sched_barrier(0);
  FC1_ASTAGE(0, 0);
  __builtin_amdgcn_sched_barrier(0);
  FC1_BLOAD(2, b1r0, b2r0);
  __builtin_amdgcn_sched_barrier(0);
  asm volatile("s_waitcnt lgkmcnt(0)" ::: "memory");   // BWRITE(0) drained

// per-iter: wait vmcnt(4) drains B(t+1)+A(t), leaves B(t+2).
// CB = t&1 compute bank, NB = CB^1.
#define FC1_STEP(T, R1, R2) do {                                             \
    const int _t = (T);                                                      \
    if (_t < NSTEP - 2) { asm volatile("s_waitcnt vmcnt(4)" ::: "memory"); } \
    else                { asm volatile("s_waitcnt vmcnt(0)" ::: "memory"); } \
    __builtin_amdgcn_s_barrier();                                            \
    __builtin_amdgcn_sched_barrier(0);                                       \
    const int _cb = _t & 1;                                                  \
    const int _nb = _cb ^ 1;                                                 \
    if (_t + 1 < NSTEP) FC1_BWRITE(_nb, R1, R2);                             \
    __builtin_amdgcn_sched_barrier(0);                                       \
    if (_t + 1 < NSTEP) FC1_ASTAGE(_nb, _t + 1);                             \
    __builtin_amdgcn_sched_barrier(0);                                       \
    if (_t + 3 < NSTEP) FC1_BLOAD(_t + 3, R1, R2);                           \
    __builtin_amdgcn_sched_barrier(0);                                       \
    bf16x8 _af[4];                                                           \
    for (int _m = 0; _m < 4; ++_m)                                           \
      _af[_m] = *(const bf16x8*)&sA[_cb][aoff[_m]];                          \
    __builtin_amdgcn_sched_barrier(0);                                       \
    i32x2 _q1lo[2], _q1hi[2], _q2lo[2], _q2hi[2];                            \
    tr_issue(b1base + _cb * 4096 + trb[0], _q1lo[0], _q1hi[0]);              \
    tr_issue(b2base + _cb * 4096 + trb[0], _q2lo[0], _q2hi[0]);              \
    __builtin_amdgcn_sched_barrier(0);                                       \
    tr_issue(b1base + _cb * 4096 + trb[1], _q1lo[1], _q1hi[1]);              \
    tr_issue(b2base + _cb * 4096 + trb[1], _q2lo[1], _q2hi[1]);              \
    asm volatile("s_waitcnt lgkmcnt(4)" ::: "memory");                       \
    __builtin_amdgcn_sched_barrier(0);                                       \
    bf16x8 _b1f0 = tr_pack(_q1lo[0], _q1hi[0]);                              \
    bf16x8 _b2f0 = tr_pack(_q2lo[0], _q2hi[0]);                              \
    __builtin_amdgcn_s_setprio(1);                                           \
    for (int _m = 0; _m < 4; ++_m) {                                         \
      acc1[_m][0] = __builtin_amdgcn_mfma_f32_16x16x32_bf16(_af[_m], _b1f0, acc1[_m][0], 0, 0, 0); \
      acc2[_m][0] = __builtin_amdgcn_mfma_f32_16x16x32_bf16(_af[_m], _b2f0, acc2[_m][0], 0, 0, 0); \
    }                                                                        \
    __builtin_amdgcn_s_setprio(0);                                           \
    asm volatile("s_waitcnt lgkmcnt(0)" ::: "memory");                       \
    __builtin_amdgcn_sched_barrier(0);                                       \
    bf16x8 _b1f1 = tr_pack(_q1lo[1], _q1hi[1]);                              \
    bf16x8 _b2f1 = tr_pack(_q2lo[1], _q2hi[1]);                              \
    __builtin_amdgcn_s_setprio(1);                                           \
    for (int _m = 0; _m < 4; ++_m) {                                         \
      acc1[_m][1] = __builtin_amdgcn_mfma_f32_16x16x32_bf16(_af[_m], _b1f1, acc1[_m][1], 0, 0, 0); \
      acc2[_m][1] = __builtin_amdgcn_mfma_f32_16x16x32_bf16(_af[_m], _b2f1, acc2[_m][1], 0, 0, 0); \
    }                                                                        \
    __builtin_amdgcn_s_setprio(0);                                           \
  } while (0)

  for (int tt = 0; tt < NSTEP; tt += 2) {
    FC1_STEP(tt, b1r1, b2r1);       // even t: bank1 regs
    FC1_STEP(tt + 1, b1r0, b2r0);   // odd t: bank0 regs
  }

  float prv[4][4];
#pragma unroll
  for (int m = 0; m < 4; ++m)
#pragma unroll
    for (int r = 0; r < 4; ++r)
      prv[m][r] = sp[rowbase + wm * 64 + m * 16 + (lane >> 4) * 4 + r];

#pragma unroll
  for (int m = 0; m < 4; ++m) {
    const int rb = rowbase + wm * 64 + m * 16 + (lane >> 4) * 4;
#pragma unroll
    for (int n = 0; n < 2; ++n) {
      const int col = n0 + wn * 32 + n * 16 + (lane & 15);
#pragma unroll
      for (int r = 0; r < 4; ++r) {
        const float y1 = acc1[m][n][r];
        const float y2 = acc2[m][n][r];
        const float gv = y1 / (1.f + __expf(-y1)) * y2 * prv[m][r];
        g[(size_t)(rb + r) * FD + col] = f2bf(gv);
      }
    }
  }
}

// ---------------------------------------------------------------------------
// fc2: o[slot] = g[slot] @ w2[e] -- 2-buffer LDS (24 KB), depth-2 B banks,
// per-iter [BWRITE | ASTAGE(t+1) | BLOAD(t+3)], steady vmcnt(2).
// ---------------------------------------------------------------------------
__global__ __launch_bounds__(256) void k_fc2(
    const unsigned short* __restrict__ g,     // [MAXSLOTS][F] bf16
    const float* __restrict__ w2,             // [E][F][H] f32 (native input)
    const int* __restrict__ ctrl,
    const int* __restrict__ widmt2,
    float* __restrict__ o)                    // [MAXSLOTS][OP] f32
{
  const int bid = blockIdx.x;
  const int wid = (bid & 7) * FC2_CHUNK + (bid >> 3);
  const int packed = widmt2[wid];
  if (packed < 0) return;
  const int mt = packed >> 5;
  const int e = ctrl[24 + mt];
  const int rowbase = ctrl[64 + mt];
  const int n0 = (packed & 31) * 64;

  __shared__ unsigned short sA[2][BM * BK];   // 16 KB
  __shared__ unsigned short sB[2][64 * BK];   // 8 KB; total 24 KB

  const int tid = threadIdx.x;
  const int lane = tid & 63;
  const int wave = tid >> 6;
  const int wm = wave >> 1, wn = wave & 1;

  const int schunk = (lane & 3) ^ ((lane >> 3) & 3);
  const unsigned short* aSrc[2];
#pragma unroll
  for (int t4 = 0; t4 < 2; ++t4) {
    const int row = (t4 * 4 + wave) * 16 + (lane >> 2);
    aSrc[t4] = g + (size_t)(rowbase + row) * FD + schunk * 8;
  }

  const int kdec = wave * 8 + ((lane >> 5) << 2) + ((lane >> 1) & 3);
  const int ndec = ((lane >> 3) & 3) * 16 + (lane & 1) * 8;
  const float* bSrcF = w2 + ((size_t)e * FD + kdec) * HD + n0 + ndec;

  const int c = lane >> 4;
  int aoff[4];
#pragma unroll
  for (int m = 0; m < 4; ++m) {
    const int row = wm * 64 + m * 16 + (lane & 15);
    aoff[m] = row * 32 + ((c ^ ((row >> 1) & 3)) << 3);
  }
  const unsigned trlane = (lane & 15) * 8 + (lane >> 4) * 1024;
  unsigned trb[2];
#pragma unroll
  for (int n = 0; n < 2; ++n) trb[n] = trlane + (wn * 2 + n) * 128;
  const unsigned bbase = LDS_OFF(&sB[0][0]);

  const f32x4 zero = {0.f, 0.f, 0.f, 0.f};
  f32x4 acc[4][2];
#pragma unroll
  for (int m = 0; m < 4; ++m)
#pragma unroll
    for (int n = 0; n < 2; ++n) acc[m][n] = zero;

  float br0[8], br1[8];

#define FC2_BLOAD(KT, R) do {                                       \
    const float* _p = bSrcF + (size_t)(KT) * BK * HD;               \
    *(float4*)&R[0] = *(const float4*)_p;                           \
    *(float4*)&R[4] = *(const float4*)(_p + 4);                     \
  } while (0)

#define FC2_BWRITE(BUF, R) do {                                     \
    unsigned _a0,_a1,_a2,_a3;                                       \
    asm("v_cvt_pk_bf16_f32 %0, %1, %2" : "=v"(_a0) : "v"(R[0]), "v"(R[1])); \
    asm("v_cvt_pk_bf16_f32 %0, %1, %2" : "=v"(_a1) : "v"(R[2]), "v"(R[3])); \
    asm("v_cvt_pk_bf16_f32 %0, %1, %2" : "=v"(_a2) : "v"(R[4]), "v"(R[5])); \
    asm("v_cvt_pk_bf16_f32 %0, %1, %2" : "=v"(_a3) : "v"(R[6]), "v"(R[7])); \
    uint4 _u = make_uint4(_a0,_a1,_a2,_a3);                         \
    *(uint4*)&sB[BUF][wave * 512 + lane * 8] = _u;                  \
  } while (0)

#define FC2_ASTAGE(BUF, KT) do {                                    \
    for (int _t4 = 0; _t4 < 2; ++_t4)                               \
      GLL16(aSrc[_t4] + (size_t)(KT) * BK, &sA[BUF][(_t4 * 4 + wave) * 512]); \
  } while (0)

  const int NSTEP = FD / BK;   // 44
  // ---- prologue: lands queue [B1:2, A0:2, B2:2] ----
  FC2_BLOAD(0, br0);
  __builtin_amdgcn_sched_barrier(0);
  asm volatile("s_waitcnt vmcnt(0)" ::: "memory");
  FC2_BWRITE(0, br0);
  __builtin_amdgcn_sched_barrier(0);
  FC2_BLOAD(1, br1);
  __builtin_amdgcn_sched_barrier(0);
  FC2_ASTAGE(0, 0);
  __builtin_amdgcn_sched_barrier(0);
  FC2_BLOAD(2, br0);
  __builtin_amdgcn_sched_barrier(0);
  asm volatile("s_waitcnt lgkmcnt(0)" ::: "memory");

#define FC2_STEP(T, R) do {                                                  \
    const int _t = (T);                                                      \
    if (_t < NSTEP - 2) { asm volatile("s_waitcnt vmcnt(2)" ::: "memory"); } \
    else                { asm volatile("s_waitcnt vmcnt(0)" ::: "memory"); } \
    __builtin_amdgcn_s_barrier();                                            \
    __builtin_amdgcn_sched_barrier(0);                                       \
    const int _cb = _t & 1;                                                  \
    const int _nb = _cb ^ 1;                                                 \
    if (_t + 1 < NSTEP) FC2_BWRITE(_nb, R);                                  \
    __builtin_amdgcn_sched_barrier(0);                                       \
    if (_t + 1 < NSTEP) FC2_ASTAGE(_nb, _t + 1);                             \
    __builtin_amdgcn_sched_barrier(0);                                       \
    if (_t + 3 < NSTEP) FC2_BLOAD(_t + 3, R);                                \
    __builtin_amdgcn_sched_barrier(0);                                       \
    bf16x8 _af[4];                                                           \
    for (int _m = 0; _m < 4; ++_m)                                           \
      _af[_m] = *(const bf16x8*)&sA[_cb][aoff[_m]];                          \
    __builtin_amdgcn_sched_barrier(0);                                       \
    i32x2 _qlo[2], _qhi[2];                                                  \
    tr_issue(bbase + _cb * 4096 + trb[0], _qlo[0], _qhi[0]);                 \
    __builtin_amdgcn_sched_barrier(0);                                       \
    tr_issue(bbase + _cb * 4096 + trb[1], _qlo[1], _qhi[1]);                 \
    asm volatile("s_waitcnt lgkmcnt(2)" ::: "memory");                       \
    __builtin_amdgcn_sched_barrier(0);                                       \
    bf16x8 _bf0 = tr_pack(_qlo[0], _qhi[0]);                                 \
    __builtin_amdgcn_s_setprio(1);                                           \
    for (int _m = 0; _m < 4; ++_m)                                           \
      acc[_m][0] = __builtin_amdgcn_mfma_f32_16x16x32_bf16(_af[_m], _bf0, acc[_m][0], 0, 0, 0); \
    __builtin_amdgcn_s_setprio(0);                                           \
    asm volatile("s_waitcnt lgkmcnt(0)" ::: "memory");                       \
    __builtin_amdgcn_sched_barrier(0);                                       \
    bf16x8 _bf1 = tr_pack(_qlo[1], _qhi[1]);                                 \
    __builtin_amdgcn_s_setprio(1);                                           \
    for (int _m = 0; _m < 4; ++_m)                                           \
      acc[_m][1] = __builtin_amdgcn_mfma_f32_16x16x32_bf16(_af[_m], _bf1, acc[_m][1], 0, 0, 0); \
    __builtin_amdgcn_s_setprio(0);                                           \
  } while (0)

  for (int tt = 0; tt < NSTEP; tt += 2) {
    FC2_STEP(tt, br1);       // even t: bank1 regs
    FC2_STEP(tt + 1, br0);   // odd t: bank0 regs
  }

#pragma unroll
  for (int m = 0; m < 4; ++m) {
    const int rb = rowbase + wm * 64 + m * 16 + (lane >> 4) * 4;
#pragma unroll
    for (int n = 0; n < 2; ++n) {
      const int col = n0 + wn * 32 + n * 16 + (lane & 15);
#pragma unroll
      for (int r = 0; r < 4; ++r)
        o[(size_t)(rb + r) * OP + col] = acc[m][n][r];
    }
  }
}

// ---------------------------------------------------------------------------
// Combine (unchanged).
// ---------------------------------------------------------------------------
__global__ __launch_bounds__(256) void k_combine(
    const float* __restrict__ o, const int* __restrict__ tslot,
    float* __restrict__ out)
{
  const int t = blockIdx.x;
  const int c4 = threadIdx.x;
  const int sA = tslot[t * 2], sB = tslot[t * 2 + 1];
  const float4 a = reinterpret_cast<const float4*>(o + (size_t)sA * OP)[c4];
  const float4 b = reinterpret_cast<const float4*>(o + (size_t)sB * OP)[c4];
  float4 r;
  r.x = a.x + b.x; r.y = a.y + b.y; r.z = a.z + b.z; r.w = a.w + b.w;
  reinterpret_cast<float4*>(out)[(size_t)t * 256 + c4] = r;
}

// ---------------------------------------------------------------------------
extern "C" void kernel_launch(void* const* d_in, const int* in_sizes, int n_in,
                              void* d_out, int out_size, void* d_ws, size_t ws_size,
                              hipStream_t stream)
{
  const float* x  = (const float*)d_in[0];   // [2048,1,1024]
  const float* rw = (const float*)d_in[1];   // [1024,8]
  const float* w1 = (const float*)d_in[2];   // [8,1024,2816]
  const float* w2 = (const float*)d_in[3];   // [8,1408,1024]
  float* out = (float*)d_out;
  char* ws = (char*)d_ws;

  // ws layout (bytes)
  int*   ctrl   = (int*)(ws + 0);
  int*   tok_e  = (int*)(ws + 1024);
  float* tok_p  = (float*)(ws + 17408);
  int*   stok   = (int*)(ws + 33792);
  float* sp     = (float*)(ws + 54272);
  int*   tslot  = (int*)(ws + 74752);
  int*   widmt1 = (int*)(ws + 91136);
  int*   widmt2 = (int*)(ws + 94656);
  unsigned short* xbf = (unsigned short*)(ws + 97280);   // [T][HP]     4.33 MB
  unsigned short* g   = (unsigned short*)(ws + 4422656); // [SLOTS][F]  14.5 MB
  float*          o   = (float*)(ws + 18840576);         // [SLOTS][OP] 21.6 MB

  hipMemsetAsync(ws, 0, 1024, stream);

  k_router<<<T_TOK / 4, 256, 0, stream>>>(x, rw, xbf, ctrl, tok_e, tok_p);
  k_offsets<<<1, 256, 0, stream>>>(ctrl, tok_e, tok_p, stok, sp, tslot, widmt1, widmt2);
  k_fc1<<<FC1_NWG, 256, 0, stream>>>(xbf, w1, ctrl, stok, sp, widmt1, g);
  k_fc2<<<FC2_NWG, 256, 0, stream>>>(g, w2, ctrl, widmt2, o);
  k_combine<<<T_TOK, 256, 0, stream>>>(o, tslot, out);
}

// Round 16
// 167.482 us; speedup vs baseline: 2.7500x; 1.0172x over previous
//
#include <hip/hip_runtime.h>
#include <hip/hip_bf16.h>
#include <stdint.h>

// Problem dims
#define T_TOK 2048
#define HD    1024
#define NE    8
#define FD    1408
#define F2D   2816
#define HP    1056     // xbf row pitch (bf16)
#define OP    1056     // o row pitch (bf16)

// GEMM tiling
#define BM 128
#define BK 32
#define MAXMT 40
#define MAXSLOTS 5120
#define FC1_NT 22      // FD/64
#define FC2_NT 16      // HD/64
#define FC1_NWG (FC1_NT * MAXMT)   // 880
#define FC2_NWG (FC2_NT * MAXMT)   // 640
#define FC1_CHUNK 110
#define FC2_CHUNK 80

typedef __attribute__((ext_vector_type(8))) short bf16x8;
typedef __attribute__((ext_vector_type(4))) float f32x4;
typedef __attribute__((ext_vector_type(2))) int i32x2;

__device__ __forceinline__ unsigned short f2bf(float f) {
  unsigned int u = __float_as_uint(f);
  u += 0x7FFFu + ((u >> 16) & 1u);   // RNE
  return (unsigned short)(u >> 16);
}
__device__ __forceinline__ float bf2f(unsigned short u) {
  return __uint_as_float(((unsigned int)u) << 16);
}

#define GLL16(gp, lp) __builtin_amdgcn_global_load_lds( \
    (const __attribute__((address_space(1))) void*)(gp), \
    (__attribute__((address_space(3))) void*)(lp), 16, 0, 0)

#define LDS_OFF(p) ((unsigned)(uintptr_t)(__attribute__((address_space(3))) const unsigned short*)(p))

// Transpose-read pair (verified r10): issue raw, wait at call site, unpack after.
__device__ __forceinline__ void tr_issue(unsigned a, i32x2& lo, i32x2& hi) {
  asm volatile("ds_read_b64_tr_b16 %0, %2\n\t"
               "ds_read_b64_tr_b16 %1, %2 offset:512"
               : "=&v"(lo), "=&v"(hi)
               : "v"(a)
               : "memory");
}
__device__ __forceinline__ bf16x8 tr_pack(i32x2 lo, i32x2 hi) {
  union { i32x2 v; short s[4]; } a, b;
  a.v = lo; b.v = hi;
  bf16x8 f;
  f[0] = a.s[0]; f[1] = a.s[1]; f[2] = a.s[2]; f[3] = a.s[3];
  f[4] = b.s[0]; f[5] = b.s[1]; f[6] = b.s[2]; f[7] = b.s[3];
  return f;
}

// ---------------------------------------------------------------------------
// Router: one wave per token. f32 logits, softmax, top-2, counts; emits x bf16.
// ---------------------------------------------------------------------------
__global__ __launch_bounds__(256) void k_router(
    const float* __restrict__ x, const float* __restrict__ rw,
    unsigned short* __restrict__ xbf, int* __restrict__ ctrl,
    int* __restrict__ tok_e, float* __restrict__ tok_p)
{
  const int lane = threadIdx.x & 63;
  const int t = blockIdx.x * 4 + (threadIdx.x >> 6);
  const float* xr = x + (size_t)t * HD;

  float part[8];
#pragma unroll
  for (int e = 0; e < 8; ++e) part[e] = 0.f;

#pragma unroll
  for (int i = 0; i < 16; ++i) {
    const int h = i * 64 + lane;
    const float xv = xr[h];
    xbf[(size_t)t * HP + h] = f2bf(xv);
    const float4* rwr = reinterpret_cast<const float4*>(rw + (size_t)h * 8);
    float4 a = rwr[0], bb = rwr[1];
    part[0] += xv * a.x; part[1] += xv * a.y; part[2] += xv * a.z; part[3] += xv * a.w;
    part[4] += xv * bb.x; part[5] += xv * bb.y; part[6] += xv * bb.z; part[7] += xv * bb.w;
  }
#pragma unroll
  for (int e = 0; e < 8; ++e) {
    float v = part[e];
#pragma unroll
    for (int d = 32; d; d >>= 1) v += __shfl_xor(v, d, 64);
    part[e] = v;
  }
  float m = part[0];
#pragma unroll
  for (int e = 1; e < 8; ++e) m = fmaxf(m, part[e]);
  float p[8], s = 0.f;
#pragma unroll
  for (int e = 0; e < 8; ++e) { p[e] = __expf(part[e] - m); s += p[e]; }
  const float inv = 1.f / s;
#pragma unroll
  for (int e = 0; e < 8; ++e) p[e] *= inv;

  int e0 = 0; float p0 = p[0];
#pragma unroll
  for (int e = 1; e < 8; ++e) if (p[e] > p0) { p0 = p[e]; e0 = e; }
  int e1 = -1; float p1 = -1.f;
#pragma unroll
  for (int e = 0; e < 8; ++e) if (e != e0 && p[e] > p1) { p1 = p[e]; e1 = e; }

  if (lane == 0) {
    tok_e[t * 2 + 0] = e0; tok_e[t * 2 + 1] = e1;
    tok_p[t * 2 + 0] = p0; tok_p[t * 2 + 1] = p1;
    atomicAdd(&ctrl[e0], 1);
    atomicAdd(&ctrl[e1], 1);
  }
}

// ---------------------------------------------------------------------------
// Offsets + scatter (merged, single block).
// ctrl: [0..7]=cnt [16..23]=off [24..63]=mtE [64..103]=mtB
// ---------------------------------------------------------------------------
__global__ __launch_bounds__(256) void k_offsets(
    int* __restrict__ ctrl, const int* __restrict__ tok_e,
    const float* __restrict__ tok_p, int* __restrict__ stok,
    float* __restrict__ sp, int* __restrict__ tslot,
    int* __restrict__ widmt1, int* __restrict__ widmt2)
{
  __shared__ int soff[8], scnt[8], sFirst[8], sNmt[8], sTake[8], sCur[8];
  __shared__ int sSpill;
  if (threadIdx.x == 0) {
    int o = 0, nm = 0, spill = 0;
    for (int e = 0; e < 8; ++e) {
      ctrl[16 + e] = o; soff[e] = o; scnt[e] = ctrl[e]; sCur[e] = 0;
      const int n = ctrl[e];
      const int nmt = (n + BM - 1) / BM;
      sFirst[e] = nm; sNmt[e] = nmt; sTake[e] = nmt < 5 ? nmt : 5;
      if (nmt > 5) spill = 1;
      for (int j = 0; j < nmt; ++j) { ctrl[24 + nm] = e; ctrl[64 + nm] = o + j * BM; ++nm; }
      o += nmt * BM;
    }
    for (int i = nm; i < MAXMT; ++i) ctrl[24 + i] = -1;
    sSpill = spill;
  }
  __syncthreads();
  for (int i = threadIdx.x; i < FC1_NWG; i += 256) {
    const int e = i / FC1_CHUNK, r = i % FC1_CHUNK;
    const int j = r / FC1_NT, n = r % FC1_NT;
    widmt1[i] = (j < sTake[e]) ? (sFirst[e] + j) * 32 + n : -1;
  }
  for (int i = threadIdx.x; i < FC2_NWG; i += 256) {
    const int e = i / FC2_CHUNK, r = i % FC2_CHUNK;
    const int j = r / FC2_NT, n = r % FC2_NT;
    widmt2[i] = (j < sTake[e]) ? (sFirst[e] + j) * 32 + n : -1;
  }
  __syncthreads();
  if (sSpill && threadIdx.x == 0) {
    int cur = 0;
    for (int e = 0; e < 8; ++e)
      for (int j = 5; j < sNmt[e]; ++j)
        for (int n = 0; n < FC1_NT; ++n) {
          while (widmt1[cur] != -1) ++cur;
          widmt1[cur] = (sFirst[e] + j) * 32 + n;
        }
    cur = 0;
    for (int e = 0; e < 8; ++e)
      for (int j = 5; j < sNmt[e]; ++j)
        for (int n = 0; n < FC2_NT; ++n) {
          while (widmt2[cur] != -1) ++cur;
          widmt2[cur] = (sFirst[e] + j) * 32 + n;
        }
  }
  for (int e = 0; e < 8; ++e) {
    const int n = scnt[e], o = soff[e];
    const int padEnd = (n + BM - 1) / BM * BM;
    for (int j = n + (int)threadIdx.x; j < padEnd; j += 256) {
      stok[o + j] = 0; sp[o + j] = 0.f;
    }
  }
  for (int i = threadIdx.x; i < T_TOK; i += 256) {
#pragma unroll
    for (int k = 0; k < 2; ++k) {
      const int e = tok_e[i * 2 + k];
      const int pos = atomicAdd(&sCur[e], 1);
      const int slot = soff[e] + pos;
      stok[slot] = i; sp[slot] = tok_p[i * 2 + k];
      tslot[i * 2 + k] = slot;
    }
  }
}

// ---------------------------------------------------------------------------
// fc1: y = X[slots] @ w1[e] (gate|up), fused silu(y1)*y2*p -> bf16 g.
// 2-buffer LDS (32 KB), depth-2 B reg-banks, per-iter
// [BWRITE | ASTAGE(t+1) | BLOAD(t+3)], steady vmcnt(4). (r15, passing)
// ---------------------------------------------------------------------------
__global__ __launch_bounds__(256) void k_fc1(
    const unsigned short* __restrict__ xbf,   // [T][HP] bf16
    const float* __restrict__ w1,             // [E][H][2F] f32 (native input)
    const int* __restrict__ ctrl,
    const int* __restrict__ stok,
    const float* __restrict__ sp,
    const int* __restrict__ widmt1,
    unsigned short* __restrict__ g)           // [MAXSLOTS][F] bf16
{
  const int bid = blockIdx.x;
  const int wid = (bid & 7) * FC1_CHUNK + (bid >> 3);
  const int packed = widmt1[wid];
  if (packed < 0) return;
  const int mt = packed >> 5;
  const int e = ctrl[24 + mt];
  const int rowbase = ctrl[64 + mt];
  const int n0 = (packed & 31) * 64;

  __shared__ unsigned short sA[2][BM * BK];   // 16 KB
  __shared__ unsigned short sB1[2][64 * BK];  // 8 KB
  __shared__ unsigned short sB2[2][64 * BK];  // 8 KB; total 32 KB

  const int tid = threadIdx.x;
  const int lane = tid & 63;
  const int wave = tid >> 6;
  const int wm = wave >> 1, wn = wave & 1;

  const int schunk = (lane & 3) ^ ((lane >> 3) & 3);
  const unsigned short* aSrc[2];
#pragma unroll
  for (int t4 = 0; t4 < 2; ++t4) {
    const int row = (t4 * 4 + wave) * 16 + (lane >> 2);
    const int tok = stok[rowbase + row];
    aSrc[t4] = xbf + (size_t)tok * HP + schunk * 8;
  }

  const int kdec = wave * 8 + ((lane >> 5) << 2) + ((lane >> 1) & 3);
  const int ndec = ((lane >> 3) & 3) * 16 + (lane & 1) * 8;
  const float* b1SrcF = w1 + ((size_t)e * HD + kdec) * F2D + n0 + ndec;
  const float* b2SrcF = b1SrcF + FD;

  const int c = lane >> 4;
  int aoff[4];
#pragma unroll
  for (int m = 0; m < 4; ++m) {
    const int row = wm * 64 + m * 16 + (lane & 15);
    aoff[m] = row * 32 + ((c ^ ((row >> 1) & 3)) << 3);
  }
  const unsigned trlane = (lane & 15) * 8 + (lane >> 4) * 1024;
  unsigned trb[2];
#pragma unroll
  for (int n = 0; n < 2; ++n) trb[n] = trlane + (wn * 2 + n) * 128;
  const unsigned b1base = LDS_OFF(&sB1[0][0]);
  const unsigned b2base = LDS_OFF(&sB2[0][0]);

  const f32x4 zero = {0.f, 0.f, 0.f, 0.f};
  f32x4 acc1[4][2], acc2[4][2];
#pragma unroll
  for (int m = 0; m < 4; ++m)
#pragma unroll
    for (int n = 0; n < 2; ++n) { acc1[m][n] = zero; acc2[m][n] = zero; }

  float b1r0[8], b2r0[8], b1r1[8], b2r1[8];

#define FC1_BLOAD(KT, R1, R2) do {                                  \
    const float* _p1 = b1SrcF + (size_t)(KT) * BK * F2D;            \
    const float* _p2 = b2SrcF + (size_t)(KT) * BK * F2D;            \
    *(float4*)&R1[0] = *(const float4*)_p1;                         \
    *(float4*)&R1[4] = *(const float4*)(_p1 + 4);                   \
    *(float4*)&R2[0] = *(const float4*)_p2;                         \
    *(float4*)&R2[4] = *(const float4*)(_p2 + 4);                   \
  } while (0)

#define FC1_BWRITE(BUF, R1, R2) do {                                \
    unsigned _a0,_a1,_a2,_a3,_c0,_c1,_c2,_c3;                       \
    asm("v_cvt_pk_bf16_f32 %0, %1, %2" : "=v"(_a0) : "v"(R1[0]), "v"(R1[1])); \
    asm("v_cvt_pk_bf16_f32 %0, %1, %2" : "=v"(_a1) : "v"(R1[2]), "v"(R1[3])); \
    asm("v_cvt_pk_bf16_f32 %0, %1, %2" : "=v"(_a2) : "v"(R1[4]), "v"(R1[5])); \
    asm("v_cvt_pk_bf16_f32 %0, %1, %2" : "=v"(_a3) : "v"(R1[6]), "v"(R1[7])); \
    asm("v_cvt_pk_bf16_f32 %0, %1, %2" : "=v"(_c0) : "v"(R2[0]), "v"(R2[1])); \
    asm("v_cvt_pk_bf16_f32 %0, %1, %2" : "=v"(_c1) : "v"(R2[2]), "v"(R2[3])); \
    asm("v_cvt_pk_bf16_f32 %0, %1, %2" : "=v"(_c2) : "v"(R2[4]), "v"(R2[5])); \
    asm("v_cvt_pk_bf16_f32 %0, %1, %2" : "=v"(_c3) : "v"(R2[6]), "v"(R2[7])); \
    uint4 _u1 = make_uint4(_a0,_a1,_a2,_a3);                        \
    uint4 _u2 = make_uint4(_c0,_c1,_c2,_c3);                        \
    *(uint4*)&sB1[BUF][wave * 512 + lane * 8] = _u1;                \
    *(uint4*)&sB2[BUF][wave * 512 + lane * 8] = _u2;                \
  } while (0)

#define FC1_ASTAGE(BUF, KT) do {                                    \
    for (int _t4 = 0; _t4 < 2; ++_t4)                               \
      GLL16(aSrc[_t4] + (size_t)(KT) * BK, &sA[BUF][(_t4 * 4 + wave) * 512]); \
  } while (0)

  const int NSTEP = HD / BK;   // 32
  FC1_BLOAD(0, b1r0, b2r0);
  __builtin_amdgcn_sched_barrier(0);
  asm volatile("s_waitcnt vmcnt(0)" ::: "memory");
  FC1_BWRITE(0, b1r0, b2r0);
  __builtin_amdgcn_sched_barrier(0);
  FC1_BLOAD(1, b1r1, b2r1);
  __builtin_amdgcn_sched_barrier(0);
  FC1_ASTAGE(0, 0);
  __builtin_amdgcn_sched_barrier(0);
  FC1_BLOAD(2, b1r0, b2r0);
  __builtin_amdgcn_sched_barrier(0);
  asm volatile("s_waitcnt lgkmcnt(0)" ::: "memory");

#define FC1_STEP(T, R1, R2) do {                                             \
    const int _t = (T);                                                      \
    if (_t < NSTEP - 2) { asm volatile("s_waitcnt vmcnt(4)" ::: "memory"); } \
    else                { asm volatile("s_waitcnt vmcnt(0)" ::: "memory"); } \
    __builtin_amdgcn_s_barrier();                                            \
    __builtin_amdgcn_sched_barrier(0);                                       \
    const int _cb = _t & 1;                                                  \
    const int _nb = _cb ^ 1;                                                 \
    if (_t + 1 < NSTEP) FC1_BWRITE(_nb, R1, R2);                             \
    __builtin_amdgcn_sched_barrier(0);                                       \
    if (_t + 1 < NSTEP) FC1_ASTAGE(_nb, _t + 1);                             \
    __builtin_amdgcn_sched_barrier(0);                                       \
    if (_t + 3 < NSTEP) FC1_BLOAD(_t + 3, R1, R2);                           \
    __builtin_amdgcn_sched_barrier(0);                                       \
    bf16x8 _af[4];                                                           \
    for (int _m = 0; _m < 4; ++_m)                                           \
      _af[_m] = *(const bf16x8*)&sA[_cb][aoff[_m]];                          \
    __builtin_amdgcn_sched_barrier(0);                                       \
    i32x2 _q1lo[2], _q1hi[2], _q2lo[2], _q2hi[2];                            \
    tr_issue(b1base + _cb * 4096 + trb[0], _q1lo[0], _q1hi[0]);              \
    tr_issue(b2base + _cb * 4096 + trb[0], _q2lo[0], _q2hi[0]);              \
    __builtin_amdgcn_sched_barrier(0);                                       \
    tr_issue(b1base + _cb * 4096 + trb[1], _q1lo[1], _q1hi[1]);              \
    tr_issue(b2base + _cb * 4096 + trb[1], _q2lo[1], _q2hi[1]);              \
    asm volatile("s_waitcnt lgkmcnt(4)" ::: "memory");                       \
    __builtin_amdgcn_sched_barrier(0);                                       \
    bf16x8 _b1f0 = tr_pack(_q1lo[0], _q1hi[0]);                              \
    bf16x8 _b2f0 = tr_pack(_q2lo[0], _q2hi[0]);                              \
    __builtin_amdgcn_s_setprio(1);                                           \
    for (int _m = 0; _m < 4; ++_m) {                                         \
      acc1[_m][0] = __builtin_amdgcn_mfma_f32_16x16x32_bf16(_af[_m], _b1f0, acc1[_m][0], 0, 0, 0); \
      acc2[_m][0] = __builtin_amdgcn_mfma_f32_16x16x32_bf16(_af[_m], _b2f0, acc2[_m][0], 0, 0, 0); \
    }                                                                        \
    __builtin_amdgcn_s_setprio(0);                                           \
    asm volatile("s_waitcnt lgkmcnt(0)" ::: "memory");                       \
    __builtin_amdgcn_sched_barrier(0);                                       \
    bf16x8 _b1f1 = tr_pack(_q1lo[1], _q1hi[1]);                              \
    bf16x8 _b2f1 = tr_pack(_q2lo[1], _q2hi[1]);                              \
    __builtin_amdgcn_s_setprio(1);                                           \
    for (int _m = 0; _m < 4; ++_m) {                                         \
      acc1[_m][1] = __builtin_amdgcn_mfma_f32_16x16x32_bf16(_af[_m], _b1f1, acc1[_m][1], 0, 0, 0); \
      acc2[_m][1] = __builtin_amdgcn_mfma_f32_16x16x32_bf16(_af[_m], _b2f1, acc2[_m][1], 0, 0, 0); \
    }                                                                        \
    __builtin_amdgcn_s_setprio(0);                                           \
  } while (0)

  for (int tt = 0; tt < NSTEP; tt += 2) {
    FC1_STEP(tt, b1r1, b2r1);
    FC1_STEP(tt + 1, b1r0, b2r0);
  }

  float prv[4][4];
#pragma unroll
  for (int m = 0; m < 4; ++m)
#pragma unroll
    for (int r = 0; r < 4; ++r)
      prv[m][r] = sp[rowbase + wm * 64 + m * 16 + (lane >> 4) * 4 + r];

#pragma unroll
  for (int m = 0; m < 4; ++m) {
    const int rb = rowbase + wm * 64 + m * 16 + (lane >> 4) * 4;
#pragma unroll
    for (int n = 0; n < 2; ++n) {
      const int col = n0 + wn * 32 + n * 16 + (lane & 15);
#pragma unroll
      for (int r = 0; r < 4; ++r) {
        const float y1 = acc1[m][n][r];
        const float y2 = acc2[m][n][r];
        const float gv = y1 / (1.f + __expf(-y1)) * y2 * prv[m][r];
        g[(size_t)(rb + r) * FD + col] = f2bf(gv);
      }
    }
  }
}

// ---------------------------------------------------------------------------
// fc2: o[slot] = g[slot] @ w2[e] -- bf16 OUTPUT (halves o traffic), 2-buffer
// LDS (24 KB), depth-2 B banks, steady vmcnt(2). (r15 schedule)
// ---------------------------------------------------------------------------
__global__ __launch_bounds__(256) void k_fc2(
    const unsigned short* __restrict__ g,     // [MAXSLOTS][F] bf16
    const float* __restrict__ w2,             // [E][F][H] f32 (native input)
    const int* __restrict__ ctrl,
    const int* __restrict__ widmt2,
    unsigned short* __restrict__ o)           // [MAXSLOTS][OP] bf16
{
  const int bid = blockIdx.x;
  const int wid = (bid & 7) * FC2_CHUNK + (bid >> 3);
  const int packed = widmt2[wid];
  if (packed < 0) return;
  const int mt = packed >> 5;
  const int e = ctrl[24 + mt];
  const int rowbase = ctrl[64 + mt];
  const int n0 = (packed & 31) * 64;

  __shared__ unsigned short sA[2][BM * BK];   // 16 KB
  __shared__ unsigned short sB[2][64 * BK];   // 8 KB; total 24 KB

  const int tid = threadIdx.x;
  const int lane = tid & 63;
  const int wave = tid >> 6;
  const int wm = wave >> 1, wn = wave & 1;

  const int schunk = (lane & 3) ^ ((lane >> 3) & 3);
  const unsigned short* aSrc[2];
#pragma unroll
  for (int t4 = 0; t4 < 2; ++t4) {
    const int row = (t4 * 4 + wave) * 16 + (lane >> 2);
    aSrc[t4] = g + (size_t)(rowbase + row) * FD + schunk * 8;
  }

  const int kdec = wave * 8 + ((lane >> 5) << 2) + ((lane >> 1) & 3);
  const int ndec = ((lane >> 3) & 3) * 16 + (lane & 1) * 8;
  const float* bSrcF = w2 + ((size_t)e * FD + kdec) * HD + n0 + ndec;

  const int c = lane >> 4;
  int aoff[4];
#pragma unroll
  for (int m = 0; m < 4; ++m) {
    const int row = wm * 64 + m * 16 + (lane & 15);
    aoff[m] = row * 32 + ((c ^ ((row >> 1) & 3)) << 3);
  }
  const unsigned trlane = (lane & 15) * 8 + (lane >> 4) * 1024;
  unsigned trb[2];
#pragma unroll
  for (int n = 0; n < 2; ++n) trb[n] = trlane + (wn * 2 + n) * 128;
  const unsigned bbase = LDS_OFF(&sB[0][0]);

  const f32x4 zero = {0.f, 0.f, 0.f, 0.f};
  f32x4 acc[4][2];
#pragma unroll
  for (int m = 0; m < 4; ++m)
#pragma unroll
    for (int n = 0; n < 2; ++n) acc[m][n] = zero;

  float br0[8], br1[8];

#define FC2_BLOAD(KT, R) do {                                       \
    const float* _p = bSrcF + (size_t)(KT) * BK * HD;               \
    *(float4*)&R[0] = *(const float4*)_p;                           \
    *(float4*)&R[4] = *(const float4*)(_p + 4);                     \
  } while (0)

#define FC2_BWRITE(BUF, R) do {                                     \
    unsigned _a0,_a1,_a2,_a3;                                       \
    asm("v_cvt_pk_bf16_f32 %0, %1, %2" : "=v"(_a0) : "v"(R[0]), "v"(R[1])); \
    asm("v_cvt_pk_bf16_f32 %0, %1, %2" : "=v"(_a1) : "v"(R[2]), "v"(R[3])); \
    asm("v_cvt_pk_bf16_f32 %0, %1, %2" : "=v"(_a2) : "v"(R[4]), "v"(R[5])); \
    asm("v_cvt_pk_bf16_f32 %0, %1, %2" : "=v"(_a3) : "v"(R[6]), "v"(R[7])); \
    uint4 _u = make_uint4(_a0,_a1,_a2,_a3);                         \
    *(uint4*)&sB[BUF][wave * 512 + lane * 8] = _u;                  \
  } while (0)

#define FC2_ASTAGE(BUF, KT) do {                                    \
    for (int _t4 = 0; _t4 < 2; ++_t4)                               \
      GLL16(aSrc[_t4] + (size_t)(KT) * BK, &sA[BUF][(_t4 * 4 + wave) * 512]); \
  } while (0)

  const int NSTEP = FD / BK;   // 44
  FC2_BLOAD(0, br0);
  __builtin_amdgcn_sched_barrier(0);
  asm volatile("s_waitcnt vmcnt(0)" ::: "memory");
  FC2_BWRITE(0, br0);
  __builtin_amdgcn_sched_barrier(0);
  FC2_BLOAD(1, br1);
  __builtin_amdgcn_sched_barrier(0);
  FC2_ASTAGE(0, 0);
  __builtin_amdgcn_sched_barrier(0);
  FC2_BLOAD(2, br0);
  __builtin_amdgcn_sched_barrier(0);
  asm volatile("s_waitcnt lgkmcnt(0)" ::: "memory");

#define FC2_STEP(T, R) do {                                                  \
    const int _t = (T);                                                      \
    if (_t < NSTEP - 2) { asm volatile("s_waitcnt vmcnt(2)" ::: "memory"); } \
    else                { asm volatile("s_waitcnt vmcnt(0)" ::: "memory"); } \
    __builtin_amdgcn_s_barrier();                                            \
    __builtin_amdgcn_sched_barrier(0);                                       \
    const int _cb = _t & 1;                                                  \
    const int _nb = _cb ^ 1;                                                 \
    if (_t + 1 < NSTEP) FC2_BWRITE(_nb, R);                                  \
    __builtin_amdgcn_sched_barrier(0);                                       \
    if (_t + 1 < NSTEP) FC2_ASTAGE(_nb, _t + 1);                             \
    __builtin_amdgcn_sched_barrier(0);                                       \
    if (_t + 3 < NSTEP) FC2_BLOAD(_t + 3, R);                                \
    __builtin_amdgcn_sched_barrier(0);                                       \
    bf16x8 _af[4];                                                           \
    for (int _m = 0; _m < 4; ++_m)                                           \
      _af[_m] = *(const bf16x8*)&sA[_cb][aoff[_m]];                          \
    __builtin_amdgcn_sched_barrier(0);                                       \
    i32x2 _qlo[2], _qhi[2];                                                  \
    tr_issue(bbase + _cb * 4096 + trb[0], _qlo[0], _qhi[0]);                 \
    __builtin_amdgcn_sched_barrier(0);                                       \
    tr_issue(bbase + _cb * 4096 + trb[1], _qlo[1], _qhi[1]);                 \
    asm volatile("s_waitcnt lgkmcnt(2)" ::: "memory");                       \
    __builtin_amdgcn_sched_barrier(0);                                       \
    bf16x8 _bf0 = tr_pack(_qlo[0], _qhi[0]);                                 \
    __builtin_amdgcn_s_setprio(1);                                           \
    for (int _m = 0; _m < 4; ++_m)                                           \
      acc[_m][0] = __builtin_amdgcn_mfma_f32_16x16x32_bf16(_af[_m], _bf0, acc[_m][0], 0, 0, 0); \
    __builtin_amdgcn_s_setprio(0);                                           \
    asm volatile("s_waitcnt lgkmcnt(0)" ::: "memory");                       \
    __builtin_amdgcn_sched_barrier(0);                                       \
    bf16x8 _bf1 = tr_pack(_qlo[1], _qhi[1]);                                 \
    __builtin_amdgcn_s_setprio(1);                                           \
    for (int _m = 0; _m < 4; ++_m)                                           \
      acc[_m][1] = __builtin_amdgcn_mfma_f32_16x16x32_bf16(_af[_m], _bf1, acc[_m][1], 0, 0, 0); \
    __builtin_amdgcn_s_setprio(0);                                           \
  } while (0)

  for (int tt = 0; tt < NSTEP; tt += 2) {
    FC2_STEP(tt, br1);
    FC2_STEP(tt + 1, br0);
  }

#pragma unroll
  for (int m = 0; m < 4; ++m) {
    const int rb = rowbase + wm * 64 + m * 16 + (lane >> 4) * 4;
#pragma unroll
    for (int n = 0; n < 2; ++n) {
      const int col = n0 + wn * 32 + n * 16 + (lane & 15);
#pragma unroll
      for (int r = 0; r < 4; ++r)
        o[(size_t)(rb + r) * OP + col] = f2bf(acc[m][n][r]);
    }
  }
}

// ---------------------------------------------------------------------------
// Combine: out[t] = o[slotA(t)] + o[slotB(t)] (bf16 in, f32 out).
// ---------------------------------------------------------------------------
__global__ __launch_bounds__(256) void k_combine(
    const unsigned short* __restrict__ o, const int* __restrict__ tslot,
    float* __restrict__ out)
{
  const int t = blockIdx.x;
  const int c4 = threadIdx.x;           // 4 cols per thread
  const int sA = tslot[t * 2], sB = tslot[t * 2 + 1];
  const ushort4 a = *reinterpret_cast<const ushort4*>(o + (size_t)sA * OP + c4 * 4);
  const ushort4 b = *reinterpret_cast<const ushort4*>(o + (size_t)sB * OP + c4 * 4);
  float4 r;
  r.x = bf2f(a.x) + bf2f(b.x);
  r.y = bf2f(a.y) + bf2f(b.y);
  r.z = bf2f(a.z) + bf2f(b.z);
  r.w = bf2f(a.w) + bf2f(b.w);
  reinterpret_cast<float4*>(out)[(size_t)t * 256 + c4] = r;
}

// ---------------------------------------------------------------------------
extern "C" void kernel_launch(void* const* d_in, const int* in_sizes, int n_in,
                              void* d_out, int out_size, void* d_ws, size_t ws_size,
                              hipStream_t stream)
{
  const float* x  = (const float*)d_in[0];   // [2048,1,1024]
  const float* rw = (const float*)d_in[1];   // [1024,8]
  const float* w1 = (const float*)d_in[2];   // [8,1024,2816]
  const float* w2 = (const float*)d_in[3];   // [8,1408,1024]
  float* out = (float*)d_out;
  char* ws = (char*)d_ws;

  // ws layout (bytes)
  int*   ctrl   = (int*)(ws + 0);
  int*   tok_e  = (int*)(ws + 1024);
  float* tok_p  = (float*)(ws + 17408);
  int*   stok   = (int*)(ws + 33792);
  float* sp     = (float*)(ws + 54272);
  int*   tslot  = (int*)(ws + 74752);
  int*   widmt1 = (int*)(ws + 91136);
  int*   widmt2 = (int*)(ws + 94656);
  unsigned short* xbf = (unsigned short*)(ws + 97280);    // [T][HP]     4.33 MB
  unsigned short* g   = (unsigned short*)(ws + 4422656);  // [SLOTS][F]  14.5 MB
  unsigned short* o   = (unsigned short*)(ws + 18840576); // [SLOTS][OP] 10.8 MB bf16

  hipMemsetAsync(ws, 0, 1024, stream);

  k_router<<<T_TOK / 4, 256, 0, stream>>>(x, rw, xbf, ctrl, tok_e, tok_p);
  k_offsets<<<1, 256, 0, stream>>>(ctrl, tok_e, tok_p, stok, sp, tslot, widmt1, widmt2);
  k_fc1<<<FC1_NWG, 256, 0, stream>>>(xbf, w1, ctrl, stok, sp, widmt1, g);
  k_fc2<<<FC2_NWG, 256, 0, stream>>>(g, w2, ctrl, widmt2, o);
  k_combine<<<T_TOK, 256, 0, stream>>>(o, tslot, out);
}